// Round 7
// baseline (21.084 us; speedup 1.0000x reference)
//
#include <hip/hip_runtime.h>

__device__ __forceinline__ float frcp(float x) { return __builtin_amdgcn_rcpf(x); }

typedef float f32x4 __attribute__((ext_vector_type(4)));

#define ROWS 512                    // rows per block (= blockDim.x)
#define BLK_F4 (ROWS * 10 / 4)      // 1280 float4 chunks per block

__global__ __launch_bounds__(512) void amber_dyn_lds(
    const f32x4* __restrict__ st4,   // state as float4 stream [B*10/4]
    const f32x4* __restrict__ u4,    // [B]
    f32x4* __restrict__ out4,        // [B*10/4]
    int B)
{
    __shared__ float lds[ROWS * 10];            // 20480 B
    f32x4* lds4 = reinterpret_cast<f32x4*>(lds);

    const int tid = threadIdx.x;
    const int f4base = blockIdx.x * BLK_F4;
    const int totalF4 = B * 10 / 4;

    const int row = blockIdx.x * ROWS + tid;
    // hoist u load (read-once -> nontemporal); latency hides under stage 1
    f32x4 uv = {0.f, 0.f, 0.f, 0.f};
    if (row < B) uv = __builtin_nontemporal_load(&u4[row]);

    // ---- stage 1: coalesced nt global read (16 B/lane) -> linear LDS b128 ----
    #pragma unroll
    for (int it = 0; it < 3; ++it) {
        int i = tid + it * ROWS;
        if (i < BLK_F4) {
            int g = f4base + i;
            if (g < totalF4) lds4[i] = __builtin_nontemporal_load(&st4[g]);
        }
    }
    __syncthreads();

    // ---- stage 2: per-thread row compute (own row only, in place) ----
    if (row < B) {
        float* myrow = lds + tid * 10;
        float q[5], qd[5];
        #pragma unroll
        for (int i = 0; i < 5; ++i) { q[i] = myrow[i]; qd[i] = myrow[5 + i]; }

        float s[5], c[5];
        #pragma unroll
        for (int i = 0; i < 5; ++i) __sincosf(q[i], &s[i], &c[i]);

        float v2 = qd[0]*qd[0] + qd[1]*qd[1] + qd[2]*qd[2] + qd[3]*qd[3] + qd[4]*qd[4];
        float coef = 0.1f * v2 + 9.8f;

        float bu[5] = {0.f, uv.x, uv.y, uv.z, uv.w};
        float r[5];
        #pragma unroll
        for (int i = 0; i < 5; ++i)
            r[i] = bu[i] - (coef * s[i] + 0.05f * qd[i]);

        // Woodbury: D = 2I + 0.3(cc^T+ss^T);
        // D^-1 r = 0.5 r - 0.25 U M^-1 U^T r,  M = (10/3)I + 0.5 U^T U
        float cc = 0.f, cs = 0.f, pc = 0.f, ps = 0.f;
        #pragma unroll
        for (int i = 0; i < 5; ++i) {
            cc += c[i]*c[i]; cs += c[i]*s[i];
            pc += c[i]*r[i]; ps += s[i]*r[i];
        }
        float ss = 5.0f - cc;                   // ci^2+si^2 = 1

        const float K = 10.0f / 3.0f;
        float m00 = K + 0.5f * cc;
        float m01 = 0.5f * cs;
        float m11 = K + 0.5f * ss;

        float idet = frcp(m00 * m11 - m01 * m01);
        float y0 = 0.25f * idet * (m11 * pc - m01 * ps);
        float y1 = 0.25f * idet * (m00 * ps - m01 * pc);

        #pragma unroll
        for (int i = 0; i < 5; ++i) {
            myrow[i]     = qd[i];
            myrow[5 + i] = 0.5f * r[i] - (c[i] * y0 + s[i] * y1);
        }
    }
    __syncthreads();

    // ---- stage 3: linear LDS b128 -> coalesced nt global write (16 B/lane) ----
    #pragma unroll
    for (int it = 0; it < 3; ++it) {
        int i = tid + it * ROWS;
        if (i < BLK_F4) {
            int g = f4base + i;
            if (g < totalF4) __builtin_nontemporal_store(lds4[i], &out4[g]);
        }
    }
}

extern "C" void kernel_launch(void* const* d_in, const int* in_sizes, int n_in,
                              void* d_out, int out_size, void* d_ws, size_t ws_size,
                              hipStream_t stream) {
    // inputs (setup_inputs order): t [1], state [B*10], u [B*4]
    const float* state = (const float*)d_in[1];
    const float* u     = (const float*)d_in[2];
    float* out = (float*)d_out;
    int B = in_sizes[1] / 10;

    int grid = (B + ROWS - 1) / ROWS;
    amber_dyn_lds<<<grid, ROWS, 0, stream>>>(
        (const f32x4*)state, (const f32x4*)u, (f32x4*)out, B);
}

// Round 8
// 20.569 us; speedup vs baseline: 1.0250x; 1.0250x over previous
//
#include <hip/hip_runtime.h>

__device__ __forceinline__ float frcp(float x) { return __builtin_amdgcn_rcpf(x); }

typedef float f32x4 __attribute__((ext_vector_type(4)));

#define ROWS 256                    // rows per block (= blockDim.x)  [R5 anchor]
#define BLK_F4 (ROWS * 10 / 4)      // 640 float4 chunks per block

__global__ __launch_bounds__(256) void amber_dyn_lds(
    const f32x4* __restrict__ st4,   // state as float4 stream [B*10/4]
    const f32x4* __restrict__ u4,    // [B]
    f32x4* __restrict__ out4,        // [B*10/4]
    int B)
{
    __shared__ float lds[ROWS * 10];            // 10240 B
    f32x4* lds4 = reinterpret_cast<f32x4*>(lds);

    const int tid = threadIdx.x;
    const int f4base = blockIdx.x * BLK_F4;
    const int totalF4 = B * 10 / 4;

    const int row = blockIdx.x * ROWS + tid;
    // hoist u load (read-once, nt); latency hides under stage 1
    f32x4 uv = {0.f, 0.f, 0.f, 0.f};
    if (row < B) uv = __builtin_nontemporal_load(&u4[row]);

    // ---- stage 1: coalesced nt global read (16 B/lane) -> linear LDS b128 ----
    #pragma unroll
    for (int it = 0; it < 3; ++it) {
        int i = tid + it * ROWS;
        if (i < BLK_F4) {
            int g = f4base + i;
            if (g < totalF4) lds4[i] = __builtin_nontemporal_load(&st4[g]);
        }
    }
    __syncthreads();

    // ---- stage 2: per-thread row compute (own row only, in place) ----
    if (row < B) {
        float* myrow = lds + tid * 10;
        float q[5], qd[5];
        #pragma unroll
        for (int i = 0; i < 5; ++i) { q[i] = myrow[i]; qd[i] = myrow[5 + i]; }

        float s[5], c[5];
        #pragma unroll
        for (int i = 0; i < 5; ++i) __sincosf(q[i], &s[i], &c[i]);

        float v2 = qd[0]*qd[0] + qd[1]*qd[1] + qd[2]*qd[2] + qd[3]*qd[3] + qd[4]*qd[4];
        float coef = 0.1f * v2 + 9.8f;

        float bu[5] = {0.f, uv.x, uv.y, uv.z, uv.w};
        float r[5];
        #pragma unroll
        for (int i = 0; i < 5; ++i)
            r[i] = bu[i] - (coef * s[i] + 0.05f * qd[i]);

        // Woodbury: D = 2I + 0.3(cc^T+ss^T);
        // D^-1 r = 0.5 r - 0.25 U M^-1 U^T r,  M = (10/3)I + 0.5 U^T U
        float cc = 0.f, cs = 0.f, pc = 0.f, ps = 0.f;
        #pragma unroll
        for (int i = 0; i < 5; ++i) {
            cc += c[i]*c[i]; cs += c[i]*s[i];
            pc += c[i]*r[i]; ps += s[i]*r[i];
        }
        float ss = 5.0f - cc;                   // ci^2+si^2 = 1

        const float K = 10.0f / 3.0f;
        float m00 = K + 0.5f * cc;
        float m01 = 0.5f * cs;
        float m11 = K + 0.5f * ss;

        float idet = frcp(m00 * m11 - m01 * m01);
        float y0 = 0.25f * idet * (m11 * pc - m01 * ps);
        float y1 = 0.25f * idet * (m00 * ps - m01 * pc);

        #pragma unroll
        for (int i = 0; i < 5; ++i) {
            myrow[i]     = qd[i];
            myrow[5 + i] = 0.5f * r[i] - (c[i] * y0 + s[i] * y1);
        }
    }
    __syncthreads();

    // ---- stage 3: linear LDS b128 -> coalesced nt global write (16 B/lane) ----
    #pragma unroll
    for (int it = 0; it < 3; ++it) {
        int i = tid + it * ROWS;
        if (i < BLK_F4) {
            int g = f4base + i;
            if (g < totalF4) __builtin_nontemporal_store(lds4[i], &out4[g]);
        }
    }
}

extern "C" void kernel_launch(void* const* d_in, const int* in_sizes, int n_in,
                              void* d_out, int out_size, void* d_ws, size_t ws_size,
                              hipStream_t stream) {
    // inputs (setup_inputs order): t [1], state [B*10], u [B*4]
    const float* state = (const float*)d_in[1];
    const float* u     = (const float*)d_in[2];
    float* out = (float*)d_out;
    int B = in_sizes[1] / 10;

    int grid = (B + ROWS - 1) / ROWS;
    amber_dyn_lds<<<grid, ROWS, 0, stream>>>(
        (const f32x4*)state, (const f32x4*)u, (f32x4*)out, B);
}